// Round 1
// baseline (1200.305 us; speedup 1.0000x reference)
//
#include <hip/hip_runtime.h>
#include <type_traits>

#define S_LEN 2048
#define HID   768
#define NHEAD 12
#define HDIM  64
#define BATCH 4

typedef __attribute__((ext_vector_type(4))) float float4v;
typedef __attribute__((ext_vector_type(8))) short short8;

__device__ __forceinline__ short f2b(float f) {
  unsigned u = __float_as_uint(f);
  u += 0x7fff + ((u >> 16) & 1);   // RNE
  return (short)(u >> 16);
}
__device__ __forceinline__ float b2f(short s) {
  return __uint_as_float(((unsigned)(unsigned short)s) << 16);
}

// ---------------- bf16 MFMA GEMM: C[MxN] = A[MxK] * B[KxN] ----------------
// A: float or bf16(short) row-major; B: float row-major; C: float or bf16.
// Block tile 64x64, BK=32, 4 waves; wave w -> 16-row strip, 4 n-tiles of 16.
template <typename TA, typename TC>
__global__ __launch_bounds__(256) void gemm_mfma(const TA* __restrict__ A,
                                                 const float* __restrict__ B,
                                                 TC* __restrict__ C,
                                                 int M, int N, int K) {
  __shared__ __align__(16) short As[64 * 40];  // [m][k], stride 40 keeps b128 align + spreads banks
  __shared__ __align__(16) short Bs[64 * 40];  // [n][k]
  const int tid  = threadIdx.x;
  const int wave = tid >> 6, lane = tid & 63;
  const int quad = lane >> 4, lm = lane & 15;
  const int m0 = blockIdx.y * 64, n0 = blockIdx.x * 64;

  float4v acc[4];
#pragma unroll
  for (int i = 0; i < 4; i++) acc[i] = (float4v)0.0f;

  for (int kb = 0; kb < K; kb += 32) {
    // stage A tile 64(m) x 32(k): consecutive threads -> consecutive k (coalesced)
#pragma unroll
    for (int i = 0; i < 8; i++) {
      int idx = i * 256 + tid;
      int am = idx >> 5, ak = idx & 31;
      short bits;
      if constexpr (std::is_same<TA, float>::value)
        bits = f2b(A[(size_t)(m0 + am) * K + kb + ak]);
      else
        bits = A[(size_t)(m0 + am) * K + kb + ak];
      As[am * 40 + ak] = bits;
    }
    // stage B tile 32(k) x 64(n) transposed into Bs[n][k]
#pragma unroll
    for (int i = 0; i < 8; i++) {
      int idx = i * 256 + tid;
      int bn = idx & 63, bk = idx >> 6;
      Bs[bn * 40 + bk] = f2b(B[(size_t)(kb + bk) * N + n0 + bn]);
    }
    __syncthreads();

    short8 a = *(const short8*)&As[(wave * 16 + lm) * 40 + quad * 8];
#pragma unroll
    for (int nt = 0; nt < 4; nt++) {
      short8 b = *(const short8*)&Bs[(nt * 16 + lm) * 40 + quad * 8];
      acc[nt] = __builtin_amdgcn_mfma_f32_16x16x32_bf16(a, b, acc[nt], 0, 0, 0);
    }
    __syncthreads();
  }

  // epilogue: D[row=quad*4+r][col=lm] per n-tile
#pragma unroll
  for (int nt = 0; nt < 4; nt++) {
#pragma unroll
    for (int r = 0; r < 4; r++) {
      int row = m0 + wave * 16 + quad * 4 + r;
      int col = n0 + nt * 16 + lm;
      float v = acc[nt][r];
      if constexpr (std::is_same<TC, float>::value)
        C[(size_t)row * N + col] = v;
      else
        C[(size_t)row * N + col] = f2b(v);
    }
  }
}

// ---------------- fp32 flash attention, causal ----------------
// Block: 256 threads = 16x16 (mq,nq); each thread owns 4x4 of S and 4x4 of O.
// One block per (b, h, 64-query tile); online softmax over 64-key tiles.
__device__ __forceinline__ int qswz(int d, int n) {
  // column-group XOR swizzle to spread staging-write banks
  return d * 64 + ((((n >> 2) ^ (d & 15)) << 2) | (n & 3));
}

__global__ __launch_bounds__(256) void attn_kernel(const short* __restrict__ qkv,
                                                   short* __restrict__ attnout) {
  __shared__ __align__(16) float Qs[64 * 64];  // [d][m] swizzled, pre-scaled
  __shared__ __align__(16) float Ks[64 * 64];  // [d][n] swizzled
  __shared__ __align__(16) float Vs[64 * 64];  // [n][d] natural
  __shared__ __align__(16) float Ps[64 * 64];  // [n][m] natural
  const int tid = threadIdx.x;
  const int qt = blockIdx.x, h = blockIdx.y, b = blockIdx.z;
  const int mq = tid >> 4, nq = tid & 15;
  const float scale = 0.125f;  // 1/sqrt(64)

  // stage Q (scaled into LDS)
#pragma unroll
  for (int i = 0; i < 16; i++) {
    int idx = i * 256 + tid;
    int d = idx & 63, m = idx >> 6;
    float v = b2f(qkv[(size_t)(b * S_LEN + qt * 64 + m) * (3 * HID) + h * HDIM + d]);
    Qs[qswz(d, m)] = v * scale;
  }

  float o[4][4];
  float mi[4], li[4];
#pragma unroll
  for (int r = 0; r < 4; r++) {
    mi[r] = -INFINITY; li[r] = 0.0f;
#pragma unroll
    for (int c = 0; c < 4; c++) o[r][c] = 0.0f;
  }

  for (int kt = 0; kt <= qt; kt++) {
    // stage K (transposed+swizzled) and V (natural)
#pragma unroll
    for (int i = 0; i < 16; i++) {
      int idx = i * 256 + tid;
      int d = idx & 63, n = idx >> 6;
      size_t rowb = (size_t)(b * S_LEN + kt * 64 + n) * (3 * HID) + h * HDIM + d;
      Ks[qswz(d, n)] = b2f(qkv[rowb + HID]);
      Vs[n * 64 + d] = b2f(qkv[rowb + 2 * HID]);
    }
    __syncthreads();

    // S = Q K^T (4x4 per thread)
    float s[4][4];
#pragma unroll
    for (int r = 0; r < 4; r++)
#pragma unroll
      for (int c = 0; c < 4; c++) s[r][c] = 0.0f;

#pragma unroll 4
    for (int d = 0; d < 64; d++) {
      float4v q = *(const float4v*)&Qs[d * 64 + ((mq ^ (d & 15)) << 2)];
      float4v k = *(const float4v*)&Ks[d * 64 + ((nq ^ (d & 15)) << 2)];
#pragma unroll
      for (int r = 0; r < 4; r++)
#pragma unroll
        for (int c = 0; c < 4; c++) s[r][c] += q[r] * k[c];
    }

    if (kt == qt) {  // causal mask within diagonal tile
#pragma unroll
      for (int r = 0; r < 4; r++)
#pragma unroll
        for (int c = 0; c < 4; c++)
          if (nq * 4 + c > mq * 4 + r) s[r][c] = -INFINITY;
    }

    // online softmax per row (reduce across the 16 nq threads, same wave)
#pragma unroll
    for (int r = 0; r < 4; r++) {
      float rmax = fmaxf(fmaxf(s[r][0], s[r][1]), fmaxf(s[r][2], s[r][3]));
#pragma unroll
      for (int off = 1; off < 16; off <<= 1)
        rmax = fmaxf(rmax, __shfl_xor(rmax, off, 16));
      float newm = fmaxf(mi[r], rmax);
      float alpha = __expf(mi[r] - newm);
      float psum = 0.0f;
#pragma unroll
      for (int c = 0; c < 4; c++) {
        s[r][c] = __expf(s[r][c] - newm);
        psum += s[r][c];
      }
#pragma unroll
      for (int off = 1; off < 16; off <<= 1)
        psum += __shfl_xor(psum, off, 16);
      li[r] = li[r] * alpha + psum;
      mi[r] = newm;
#pragma unroll
      for (int c = 0; c < 4; c++) o[r][c] *= alpha;
    }

    // write P transposed: Ps[n][m]
#pragma unroll
    for (int c = 0; c < 4; c++) {
      float4v pw = {s[0][c], s[1][c], s[2][c], s[3][c]};
      *(float4v*)&Ps[(nq * 4 + c) * 64 + mq * 4] = pw;
    }
    __syncthreads();

    // O += P V
#pragma unroll 4
    for (int kk = 0; kk < 64; kk++) {
      float4v p = *(const float4v*)&Ps[kk * 64 + mq * 4];
      float4v v = *(const float4v*)&Vs[kk * 64 + nq * 4];
#pragma unroll
      for (int r = 0; r < 4; r++)
#pragma unroll
        for (int c = 0; c < 4; c++) o[r][c] += p[r] * v[c];
    }
    __syncthreads();
  }

  // normalize + write bf16 [b*S+s][h*64+d]
#pragma unroll
  for (int r = 0; r < 4; r++) {
    float inv = 1.0f / li[r];
    int row = b * S_LEN + qt * 64 + mq * 4 + r;
#pragma unroll
    for (int c = 0; c < 4; c++)
      attnout[(size_t)row * HID + h * HDIM + nq * 4 + c] = f2b(o[r][c] * inv);
  }
}

extern "C" void kernel_launch(void* const* d_in, const int* in_sizes, int n_in,
                              void* d_out, int out_size, void* d_ws, size_t ws_size,
                              hipStream_t stream) {
  const float* x     = (const float*)d_in[0];
  const float* w_qkv = (const float*)d_in[1];
  const float* w_out = (const float*)d_in[2];
  float* out = (float*)d_out;

  const int M = BATCH * S_LEN;  // 8192
  short* qkv  = (short*)d_ws;                      // [8192][2304] bf16
  short* attn = qkv + (size_t)M * 3 * HID;         // [8192][768]  bf16

  // 1) qkv = x @ w_qkv  (8192x768 @ 768x2304)
  gemm_mfma<float, short><<<dim3(3 * HID / 64, M / 64), 256, 0, stream>>>(
      x, w_qkv, qkv, M, 3 * HID, HID);
  // 2) causal flash attention
  attn_kernel<<<dim3(S_LEN / 64, NHEAD, BATCH), 256, 0, stream>>>(qkv, attn);
  // 3) out = attn @ w_out  (8192x768 @ 768x768)
  gemm_mfma<short, float><<<dim3(HID / 64, M / 64), 256, 0, stream>>>(
      attn, w_out, out, M, HID, HID);
}

// Round 2
// 494.029 us; speedup vs baseline: 2.4296x; 2.4296x over previous
//
#include <hip/hip_runtime.h>
#include <type_traits>

#define S_LEN 2048
#define HID   768
#define NHEAD 12
#define HDIM  64
#define BATCH 4

typedef __attribute__((ext_vector_type(4))) float float4v;
typedef __attribute__((ext_vector_type(8))) short short8;
typedef __attribute__((ext_vector_type(4))) short short4v;

__device__ __forceinline__ short f2b(float f) {
  unsigned u = __float_as_uint(f);
  u += 0x7fff + ((u >> 16) & 1);   // RNE
  return (short)(u >> 16);
}
__device__ __forceinline__ float b2f(short s) {
  return __uint_as_float(((unsigned)(unsigned short)s) << 16);
}

// ---------------- bf16 MFMA GEMM: C[MxN] = A[MxK] * B[KxN] ----------------
template <typename TA, typename TC>
__global__ __launch_bounds__(256) void gemm_mfma(const TA* __restrict__ A,
                                                 const float* __restrict__ B,
                                                 TC* __restrict__ C,
                                                 int M, int N, int K) {
  __shared__ __align__(16) short As[64 * 40];  // [m][k]
  __shared__ __align__(16) short Bs[64 * 40];  // [n][k]
  const int tid  = threadIdx.x;
  const int wave = tid >> 6, lane = tid & 63;
  const int quad = lane >> 4, lm = lane & 15;
  const int m0 = blockIdx.y * 64, n0 = blockIdx.x * 64;

  float4v acc[4];
#pragma unroll
  for (int i = 0; i < 4; i++) acc[i] = (float4v)0.0f;

  for (int kb = 0; kb < K; kb += 32) {
#pragma unroll
    for (int i = 0; i < 8; i++) {
      int idx = i * 256 + tid;
      int am = idx >> 5, ak = idx & 31;
      short bits;
      if constexpr (std::is_same<TA, float>::value)
        bits = f2b(A[(size_t)(m0 + am) * K + kb + ak]);
      else
        bits = A[(size_t)(m0 + am) * K + kb + ak];
      As[am * 40 + ak] = bits;
    }
#pragma unroll
    for (int i = 0; i < 8; i++) {
      int idx = i * 256 + tid;
      int bn = idx & 63, bk = idx >> 6;
      Bs[bn * 40 + bk] = f2b(B[(size_t)(kb + bk) * N + n0 + bn]);
    }
    __syncthreads();

    short8 a = *(const short8*)&As[(wave * 16 + lm) * 40 + quad * 8];
#pragma unroll
    for (int nt = 0; nt < 4; nt++) {
      short8 b = *(const short8*)&Bs[(nt * 16 + lm) * 40 + quad * 8];
      acc[nt] = __builtin_amdgcn_mfma_f32_16x16x32_bf16(a, b, acc[nt], 0, 0, 0);
    }
    __syncthreads();
  }

#pragma unroll
  for (int nt = 0; nt < 4; nt++) {
#pragma unroll
    for (int r = 0; r < 4; r++) {
      int row = m0 + wave * 16 + quad * 4 + r;
      int col = n0 + nt * 16 + lm;
      float v = acc[nt][r];
      if constexpr (std::is_same<TC, float>::value)
        C[(size_t)row * N + col] = v;
      else
        C[(size_t)row * N + col] = f2b(v);
    }
  }
}

// ---------------- MFMA flash attention, causal ----------------
// Block = 4 waves, one (b, h, 64-query tile). Wave w owns q-rows w*16..w*16+15.
// QK^T and PV via mfma_f32_16x16x32_bf16; P round-trips LDS (C-layout -> A-layout).
#define PSTR 72  // LDS row stride in shorts: 144 B = 16B-aligned, banks shift 4/row

__global__ __launch_bounds__(256) void attn_mfma(const short* __restrict__ qkv,
                                                 short* __restrict__ attnout) {
  __shared__ __align__(16) short Qs[64 * PSTR];      // [m][d]
  __shared__ __align__(16) short Ks[64 * PSTR];      // [key][d]
  __shared__ __align__(16) short Vt[64 * PSTR];      // [d][key]
  __shared__ __align__(16) short Ps[4][16 * PSTR];   // per-wave [m][key]

  const int tid = threadIdx.x;
  const int wave = tid >> 6, lane = tid & 63;
  const int quad = lane >> 4, lm = lane & 15;
  const int qt = blockIdx.x, h = blockIdx.y, b = blockIdx.z;
  const float scale = 0.125f;  // 1/sqrt(64)

  // stage Q tile: 64 rows x 64 d, short4 vectorized
#pragma unroll
  for (int i = 0; i < 4; i++) {
    int idx = i * 256 + tid;
    int m = idx >> 4, c = idx & 15;
    short4v v = *(const short4v*)&qkv[(size_t)(b * S_LEN + qt * 64 + m) * (3 * HID) + h * HDIM + c * 4];
    *(short4v*)&Qs[m * PSTR + c * 4] = v;
  }

  float4v o_acc[4];
#pragma unroll
  for (int i = 0; i < 4; i++) o_acc[i] = (float4v)0.0f;
  float mi[4], li[4];
#pragma unroll
  for (int r = 0; r < 4; r++) { mi[r] = -INFINITY; li[r] = 0.0f; }

  for (int kt = 0; kt <= qt; kt++) {
    // stage K natural [key][d] and V transposed [d][key]
    __syncthreads();
#pragma unroll
    for (int i = 0; i < 4; i++) {
      int idx = i * 256 + tid;
      int key = idx >> 4, c = idx & 15;
      size_t rowb = (size_t)(b * S_LEN + kt * 64 + key) * (3 * HID) + h * HDIM + c * 4;
      short4v kv = *(const short4v*)&qkv[rowb + HID];
      *(short4v*)&Ks[key * PSTR + c * 4] = kv;
      short4v vv = *(const short4v*)&qkv[rowb + 2 * HID];
#pragma unroll
      for (int j = 0; j < 4; j++) Vt[(c * 4 + j) * PSTR + key] = vv[j];
    }
    __syncthreads();

    // S = Q K^T : 4 n-tiles x 2 k-blocks
    float4v s_acc[4];
#pragma unroll
    for (int i = 0; i < 4; i++) s_acc[i] = (float4v)0.0f;
#pragma unroll
    for (int kb = 0; kb < 2; kb++) {
      short8 a = *(const short8*)&Qs[(wave * 16 + lm) * PSTR + kb * 32 + quad * 8];
#pragma unroll
      for (int nt = 0; nt < 4; nt++) {
        short8 bk = *(const short8*)&Ks[(nt * 16 + lm) * PSTR + kb * 32 + quad * 8];
        s_acc[nt] = __builtin_amdgcn_mfma_f32_16x16x32_bf16(a, bk, s_acc[nt], 0, 0, 0);
      }
    }

    // scale + causal mask (diagonal tile only)
    if (kt == qt) {
#pragma unroll
      for (int nt = 0; nt < 4; nt++)
#pragma unroll
        for (int r = 0; r < 4; r++)
          s_acc[nt][r] = (nt * 16 + lm > wave * 16 + quad * 4 + r)
                             ? -INFINITY : s_acc[nt][r] * scale;
    } else {
#pragma unroll
      for (int nt = 0; nt < 4; nt++)
#pragma unroll
        for (int r = 0; r < 4; r++) s_acc[nt][r] *= scale;
    }

    // online softmax per row (row = quad*4+r, spread over 16-lane lm group)
#pragma unroll
    for (int r = 0; r < 4; r++) {
      float rmax = fmaxf(fmaxf(s_acc[0][r], s_acc[1][r]), fmaxf(s_acc[2][r], s_acc[3][r]));
#pragma unroll
      for (int off = 1; off < 16; off <<= 1)
        rmax = fmaxf(rmax, __shfl_xor(rmax, off, 16));
      float newm = fmaxf(mi[r], rmax);
      float alpha = __expf(mi[r] - newm);
      float psum = 0.0f;
#pragma unroll
      for (int nt = 0; nt < 4; nt++) {
        float e = __expf(s_acc[nt][r] - newm);
        s_acc[nt][r] = e;
        psum += e;
      }
#pragma unroll
      for (int off = 1; off < 16; off <<= 1)
        psum += __shfl_xor(psum, off, 16);
      li[r] = li[r] * alpha + psum;
      mi[r] = newm;
#pragma unroll
      for (int nt = 0; nt < 4; nt++) o_acc[nt][r] *= alpha;
    }

    // P (C-layout) -> per-wave LDS [m][key] (A-layout source)
#pragma unroll
    for (int nt = 0; nt < 4; nt++)
#pragma unroll
      for (int r = 0; r < 4; r++)
        Ps[wave][(quad * 4 + r) * PSTR + nt * 16 + lm] = f2b(s_acc[nt][r]);

    // O += P V  (same-wave LDS write->read; lgkmcnt handles ordering)
#pragma unroll
    for (int kb = 0; kb < 2; kb++) {
      short8 a = *(const short8*)&Ps[wave][lm * PSTR + kb * 32 + quad * 8];
#pragma unroll
      for (int nt = 0; nt < 4; nt++) {
        short8 bv = *(const short8*)&Vt[(nt * 16 + lm) * PSTR + kb * 32 + quad * 8];
        o_acc[nt] = __builtin_amdgcn_mfma_f32_16x16x32_bf16(a, bv, o_acc[nt], 0, 0, 0);
      }
    }
  }

  // normalize + write bf16 [b*S+s][h*64+d]
#pragma unroll
  for (int r = 0; r < 4; r++) {
    float inv = 1.0f / li[r];
    int row = b * S_LEN + qt * 64 + wave * 16 + quad * 4 + r;
#pragma unroll
    for (int nt = 0; nt < 4; nt++)
      attnout[(size_t)row * HID + h * HDIM + nt * 16 + lm] = f2b(o_acc[nt][r] * inv);
  }
}

extern "C" void kernel_launch(void* const* d_in, const int* in_sizes, int n_in,
                              void* d_out, int out_size, void* d_ws, size_t ws_size,
                              hipStream_t stream) {
  const float* x     = (const float*)d_in[0];
  const float* w_qkv = (const float*)d_in[1];
  const float* w_out = (const float*)d_in[2];
  float* out = (float*)d_out;

  const int M = BATCH * S_LEN;  // 8192
  short* qkv  = (short*)d_ws;                      // [8192][2304] bf16
  short* attn = qkv + (size_t)M * 3 * HID;         // [8192][768]  bf16

  gemm_mfma<float, short><<<dim3(3 * HID / 64, M / 64), 256, 0, stream>>>(
      x, w_qkv, qkv, M, 3 * HID, HID);
  attn_mfma<<<dim3(S_LEN / 64, NHEAD, BATCH), 256, 0, stream>>>(qkv, attn);
  gemm_mfma<short, float><<<dim3(HID / 64, M / 64), 256, 0, stream>>>(
      attn, w_out, out, M, HID, HID);
}

// Round 3
// 439.299 us; speedup vs baseline: 2.7323x; 1.1246x over previous
//
#include <hip/hip_runtime.h>
#include <type_traits>

#define S_LEN 2048
#define HID   768
#define NHEAD 12
#define HDIM  64
#define BATCH 4

typedef __attribute__((ext_vector_type(4))) float float4v;
typedef __attribute__((ext_vector_type(8))) short short8;
typedef __attribute__((ext_vector_type(4))) short short4v;

__device__ __forceinline__ short f2b(float f) {
  unsigned u = __float_as_uint(f);
  u += 0x7fff + ((u >> 16) & 1);   // RNE
  return (short)(u >> 16);
}
__device__ __forceinline__ float b2f(short s) {
  return __uint_as_float(((unsigned)(unsigned short)s) << 16);
}

// ---------------- bf16 MFMA GEMM: C[MxN] = A[MxK] * B[KxN] ----------------
// QKV=1: N=2304 epilogue — Q cols scaled 0.125, K cols plain, V cols -> vT[b][h][d][s].
template <typename TA, typename TC, int QKV>
__global__ __launch_bounds__(256) void gemm_mfma(const TA* __restrict__ A,
                                                 const float* __restrict__ B,
                                                 TC* __restrict__ C,
                                                 short* __restrict__ vT,
                                                 int M, int N, int K) {
  __shared__ __align__(16) short As[64 * 40];  // [m][k]
  __shared__ __align__(16) short Bs[64 * 40];  // [n][k], k XOR-swizzled
  const int tid  = threadIdx.x;
  const int wave = tid >> 6, lane = tid & 63;
  const int quad = lane >> 4, lm = lane & 15;
  const int m0 = blockIdx.y * 64, n0 = blockIdx.x * 64;

  float4v acc[4];
#pragma unroll
  for (int i = 0; i < 4; i++) acc[i] = (float4v)0.0f;

  for (int kb = 0; kb < K; kb += 32) {
#pragma unroll
    for (int i = 0; i < 8; i++) {
      int idx = i * 256 + tid;
      int am = idx >> 5, ak = idx & 31;
      short bits;
      if constexpr (std::is_same<TA, float>::value)
        bits = f2b(A[(size_t)(m0 + am) * K + kb + ak]);
      else
        bits = A[(size_t)(m0 + am) * K + kb + ak];
      As[am * 40 + ak] = bits;
    }
#pragma unroll
    for (int i = 0; i < 8; i++) {
      int idx = i * 256 + tid;
      int bn = idx & 63, bk = idx >> 6;
      Bs[bn * 40 + (bk ^ ((bn & 3) << 3))] = f2b(B[(size_t)(kb + bk) * N + n0 + bn]);
    }
    __syncthreads();

    short8 a = *(const short8*)&As[(wave * 16 + lm) * 40 + quad * 8];
#pragma unroll
    for (int nt = 0; nt < 4; nt++) {
      int n = nt * 16 + lm;
      short8 b = *(const short8*)&Bs[n * 40 + ((quad ^ (n & 3)) << 3)];
      acc[nt] = __builtin_amdgcn_mfma_f32_16x16x32_bf16(a, b, acc[nt], 0, 0, 0);
    }
    __syncthreads();
  }

  if constexpr (QKV) {
    if (n0 >= 2 * HID) {  // V columns -> vT[b][h][d][s]
      int bb = m0 >> 11;
      int s0 = (m0 & 2047) + wave * 16 + quad * 4;
#pragma unroll
      for (int nt = 0; nt < 4; nt++) {
        int col = n0 - 2 * HID + nt * 16 + lm;
        int h = col >> 6, d = col & 63;
        short4v pv;
#pragma unroll
        for (int r = 0; r < 4; r++) pv[r] = f2b(acc[nt][r]);
        *(short4v*)&vT[((size_t)(bb * NHEAD + h) * HDIM + d) * S_LEN + s0] = pv;
      }
    } else {
      float sc = (n0 < HID) ? 0.125f : 1.0f;  // fold 1/sqrt(64) into Q
#pragma unroll
      for (int nt = 0; nt < 4; nt++)
#pragma unroll
        for (int r = 0; r < 4; r++)
          C[(size_t)(m0 + wave * 16 + quad * 4 + r) * N + n0 + nt * 16 + lm] =
              f2b(acc[nt][r] * sc);
    }
  } else {
#pragma unroll
    for (int nt = 0; nt < 4; nt++)
#pragma unroll
      for (int r = 0; r < 4; r++) {
        int row = m0 + wave * 16 + quad * 4 + r;
        int col = n0 + nt * 16 + lm;
        float v = acc[nt][r];
        if constexpr (std::is_same<TC, float>::value)
          C[(size_t)row * N + col] = v;
        else
          C[(size_t)row * N + col] = f2b(v);
      }
  }
}

// ---------------- MFMA flash attention, causal, fixed-max softmax ----------------
// Block = 4 waves, 128 queries (2 m-tiles of 64). K-tile 64. No per-kt reductions.
// Ks rows key-permuted (row p <-> key 4*(p&15)+(p>>4)) so P writes are contiguous b64.
#define QTILE 128
#define PST   72   // LDS row stride (shorts): 144 B, 16B-aligned, 2-way banks (free)

__global__ __launch_bounds__(256) void attn_mfma(const short* __restrict__ qkv,
                                                 const short* __restrict__ vT,
                                                 short* __restrict__ attnout) {
  __shared__ __align__(16) short Qs[QTILE * PST];   // [m][d]
  __shared__ __align__(16) short Ks[64 * PST];      // [p][d], p key-permuted
  __shared__ __align__(16) short Vt[64 * PST];      // [d][key]
  __shared__ __align__(16) short Ps[4][16 * PST];   // per-wave [m][key]

  const int tid = threadIdx.x;
  const int w = tid >> 6, lane = tid & 63;
  const int quad = lane >> 4, lm = lane & 15;
  const int bh = blockIdx.x, qt = blockIdx.y;
  const int b = bh / NHEAD, h = bh % NHEAD;

  const size_t qbase = (size_t)(b * S_LEN + qt * QTILE) * (3 * HID) + h * HDIM;
  const size_t kbase = (size_t)(b * S_LEN) * (3 * HID) + HID + h * HDIM;
  const size_t vbase = (size_t)(b * NHEAD + h) * HDIM * S_LEN;

  // stage Q (pre-scaled by GEMM1)
#pragma unroll
  for (int i = 0; i < 4; i++) {
    int flat = i * 256 + tid;
    int row = flat >> 3, c8 = (flat & 7) * 8;
    *(short8*)&Qs[row * PST + c8] =
        *(const short8*)&qkv[qbase + (size_t)row * (3 * HID) + c8];
  }

  float4v o_acc[2][4];
#pragma unroll
  for (int mt = 0; mt < 2; mt++)
#pragma unroll
    for (int nt = 0; nt < 4; nt++) o_acc[mt][nt] = (float4v)0.0f;
  float lsum[2][4];
#pragma unroll
  for (int mt = 0; mt < 2; mt++)
#pragma unroll
    for (int r = 0; r < 4; r++) lsum[mt][r] = 0.0f;

  const int ktmax = 2 * qt + 2;
  short8 kreg[2], vreg[2];

#define PREFETCH(KT)                                                              \
  {                                                                               \
    _Pragma("unroll") for (int i = 0; i < 2; i++) {                               \
      int flat = i * 256 + tid;                                                   \
      int p = flat >> 3, c8 = (flat & 7) * 8;                                     \
      int key = 4 * (p & 15) + (p >> 4);                                          \
      kreg[i] = *(const short8*)&qkv[kbase + (size_t)((KT)*64 + key) * (3*HID) + c8]; \
      vreg[i] = *(const short8*)&vT[vbase + (size_t)p * S_LEN + (KT)*64 + c8];    \
    }                                                                             \
  }

  PREFETCH(0);

  for (int kt = 0; kt < ktmax; kt++) {
    __syncthreads();
#pragma unroll
    for (int i = 0; i < 2; i++) {
      int flat = i * 256 + tid;
      int p = flat >> 3, c8 = (flat & 7) * 8;
      *(short8*)&Ks[p * PST + c8] = kreg[i];
      *(short8*)&Vt[p * PST + c8] = vreg[i];
    }
    __syncthreads();
    if (kt + 1 < ktmax) PREFETCH(kt + 1);

#pragma unroll
    for (int mt = 0; mt < 2; mt++) {
      if (mt == 0 && kt == ktmax - 1) continue;  // fully-masked tile
      float4v s_acc[4];
#pragma unroll
      for (int i = 0; i < 4; i++) s_acc[i] = (float4v)0.0f;
#pragma unroll
      for (int kb = 0; kb < 2; kb++) {
        short8 a = *(const short8*)&Qs[(mt * 64 + w * 16 + lm) * PST + kb * 32 + quad * 8];
#pragma unroll
        for (int nt = 0; nt < 4; nt++) {
          short8 bk = *(const short8*)&Ks[(nt * 16 + lm) * PST + kb * 32 + quad * 8];
          s_acc[nt] = __builtin_amdgcn_mfma_f32_16x16x32_bf16(a, bk, s_acc[nt], 0, 0, 0);
        }
      }

      const bool diag = (kt == 2 * qt + mt);
#pragma unroll
      for (int r = 0; r < 4; r++) {
        short4v p4;
#pragma unroll
        for (int nt = 0; nt < 4; nt++) {
          float e = __expf(s_acc[nt][r]);  // fixed-max softmax: exact, no reductions
          if (diag && (4 * lm + nt > w * 16 + quad * 4 + r)) e = 0.0f;
          lsum[mt][r] += e;
          p4[nt] = f2b(e);
        }
        *(short4v*)&Ps[w][(quad * 4 + r) * PST + lm * 4] = p4;  // key = 4*lm+nt
      }

#pragma unroll
      for (int kb = 0; kb < 2; kb++) {
        short8 a = *(const short8*)&Ps[w][lm * PST + kb * 32 + quad * 8];
#pragma unroll
        for (int nt = 0; nt < 4; nt++) {
          short8 bv = *(const short8*)&Vt[(nt * 16 + lm) * PST + kb * 32 + quad * 8];
          o_acc[mt][nt] = __builtin_amdgcn_mfma_f32_16x16x32_bf16(a, bv, o_acc[mt][nt], 0, 0, 0);
        }
      }
    }
  }

  // one final row-sum reduction across the 16-lane lm group
#pragma unroll
  for (int mt = 0; mt < 2; mt++)
#pragma unroll
    for (int r = 0; r < 4; r++) {
#pragma unroll
      for (int off = 1; off < 16; off <<= 1)
        lsum[mt][r] += __shfl_xor(lsum[mt][r], off, 16);
      float inv = 1.0f / lsum[mt][r];
      int rowg = b * S_LEN + qt * QTILE + mt * 64 + w * 16 + quad * 4 + r;
#pragma unroll
      for (int nt = 0; nt < 4; nt++)
        attnout[(size_t)rowg * HID + h * HDIM + nt * 16 + lm] =
            f2b(o_acc[mt][nt][r] * inv);
    }
}

extern "C" void kernel_launch(void* const* d_in, const int* in_sizes, int n_in,
                              void* d_out, int out_size, void* d_ws, size_t ws_size,
                              hipStream_t stream) {
  const float* x     = (const float*)d_in[0];
  const float* w_qkv = (const float*)d_in[1];
  const float* w_out = (const float*)d_in[2];
  float* out = (float*)d_out;

  const int M = BATCH * S_LEN;  // 8192
  short* qkv  = (short*)d_ws;                        // [8192][2304] bf16 (V third unused)
  short* attn = qkv + (size_t)M * 3 * HID;           // [8192][768]  bf16
  short* vT   = attn + (size_t)M * HID;              // [B][NH][64][2048] bf16

  gemm_mfma<float, short, 1><<<dim3(3 * HID / 64, M / 64), 256, 0, stream>>>(
      x, w_qkv, qkv, vT, M, 3 * HID, HID);
  attn_mfma<<<dim3(BATCH * NHEAD, S_LEN / QTILE), 256, 0, stream>>>(qkv, vT, attn);
  gemm_mfma<short, float, 0><<<dim3(HID / 64, M / 64), 256, 0, stream>>>(
      attn, w_out, out, nullptr, M, HID, HID);
}

// Round 4
// 232.365 us; speedup vs baseline: 5.1656x; 1.8906x over previous
//
#include <hip/hip_runtime.h>
#include <type_traits>

#define S_LEN 2048
#define HID   768
#define NHEAD 12
#define HDIM  64
#define BATCH 4

typedef __attribute__((ext_vector_type(4))) float float4v;
typedef __attribute__((ext_vector_type(8))) short short8;
typedef __attribute__((ext_vector_type(4))) short short4v;

__device__ __forceinline__ short f2b(float f) {
  unsigned u = __float_as_uint(f);
  u += 0x7fff + ((u >> 16) & 1);   // RNE
  return (short)(u >> 16);
}
__device__ __forceinline__ float b2f(short s) {
  return __uint_as_float(((unsigned)(unsigned short)s) << 16);
}

// async global->LDS, 16 B per lane; lds base must be wave-uniform
__device__ __forceinline__ void g2l16(const short* g, short* l) {
  __builtin_amdgcn_global_load_lds(
      (const __attribute__((address_space(1))) void*)g,
      (__attribute__((address_space(3))) void*)l, 16, 0, 0);
}

// ---------------- pre-pass: fp32 -> bf16 convert ----------------
__global__ __launch_bounds__(256) void cvt_bf16(const float* __restrict__ X,
                                                short* __restrict__ Xb) {
  int i = (blockIdx.x * 256 + threadIdx.x) * 8;
  float4v a = *(const float4v*)&X[i];
  float4v b = *(const float4v*)&X[i + 4];
  short8 o;
#pragma unroll
  for (int j = 0; j < 4; j++) { o[j] = f2b(a[j]); o[j + 4] = f2b(b[j]); }
  *(short8*)&Xb[i] = o;
}

// ---------------- pre-pass: W[K_][N_] f32 -> WT[N_][K_] bf16 (+row scale) ----
__global__ __launch_bounds__(256) void transpose_w(const float* __restrict__ W,
                                                   short* __restrict__ WT,
                                                   int K_, int N_, int scaleN) {
  __shared__ float tile[64][65];
  const int n0 = blockIdx.x * 64, k0 = blockIdx.y * 64;
  const int tx = threadIdx.x & 63, ty = threadIdx.x >> 6;
#pragma unroll
  for (int r = 0; r < 16; r++) {
    int row = r * 4 + ty;
    tile[row][tx] = W[(size_t)(k0 + row) * N_ + n0 + tx];
  }
  __syncthreads();
#pragma unroll
  for (int r = 0; r < 16; r++) {
    int row = r * 4 + ty;
    float sc = (n0 + row < scaleN) ? 0.125f : 1.0f;
    WT[(size_t)(n0 + row) * K_ + k0 + tx] = f2b(tile[tx][row] * sc);
  }
}

// ---------------- m97-style bf16 GEMM: C[MxN] = A[MxK] * Bt[NxK]^T ----------
// 128x128 tile, BK=32, 4 waves (64x64 quadrant each), global_load_lds staging.
// OUT=0: float C.  OUT=1: QKV epilogue (Q/K -> qk[m][1536], V -> vT[b][h][d][s]).
template <int OUT>
__global__ __launch_bounds__(256) void gemm_bt(const short* __restrict__ A,
                                               const short* __restrict__ Bt,
                                               float* __restrict__ Cf,
                                               short* __restrict__ Cq,
                                               short* __restrict__ vT,
                                               int M, int N, int K) {
  __shared__ __align__(16) short As[128 * 32];  // [m][k] contiguous (g2l16 layout)
  __shared__ __align__(16) short Bs[128 * 32];  // [n][k] contiguous
  const int tid = threadIdx.x;
  const int w = tid >> 6, lane = tid & 63;
  const int quad = lane >> 4, lm = lane & 15;
  const int m0 = blockIdx.y * 128, n0 = blockIdx.x * 128;
  const int mo = (w & 1) * 64, no = (w >> 1) * 64;

  float4v acc[4][4];
#pragma unroll
  for (int i = 0; i < 4; i++)
#pragma unroll
    for (int j = 0; j < 4; j++) acc[i][j] = (float4v)0.0f;

  // staging addresses: wave w stages rows [w*32, w*32+32) of each tile
  const int srow = w * 32 + (lane >> 2);
  const int scol = (lane & 3) * 8;  // shorts
  const short* Ag = A + (size_t)(m0 + srow) * K + scol;
  const short* Bg = Bt + (size_t)(n0 + srow) * K + scol;
  short* Al = &As[(w * 32) * 32];  // wave-uniform; HW adds lane*16B
  short* Bl = &Bs[(w * 32) * 32];

  for (int kb = 0; kb < K; kb += 32) {
    g2l16(Ag + kb, Al);
    g2l16(Ag + kb + (size_t)16 * K, Al + 16 * 32);
    g2l16(Bg + kb, Bl);
    g2l16(Bg + kb + (size_t)16 * K, Bl + 16 * 32);
    __syncthreads();

    short8 af[4], bf[4];
#pragma unroll
    for (int i = 0; i < 4; i++)
      af[i] = *(const short8*)&As[(mo + i * 16 + lm) * 32 + quad * 8];
#pragma unroll
    for (int j = 0; j < 4; j++)
      bf[j] = *(const short8*)&Bs[(no + j * 16 + lm) * 32 + quad * 8];
#pragma unroll
    for (int i = 0; i < 4; i++)
#pragma unroll
      for (int j = 0; j < 4; j++)
        acc[i][j] = __builtin_amdgcn_mfma_f32_16x16x32_bf16(af[i], bf[j], acc[i][j], 0, 0, 0);
    __syncthreads();
  }

  if constexpr (OUT == 0) {
#pragma unroll
    for (int i = 0; i < 4; i++)
#pragma unroll
      for (int j = 0; j < 4; j++)
#pragma unroll
        for (int r = 0; r < 4; r++)
          Cf[(size_t)(m0 + mo + i * 16 + quad * 4 + r) * N + n0 + no + j * 16 + lm] =
              acc[i][j][r];
  } else {
    if (n0 >= 2 * HID) {  // V tile -> vT[b][h][d][s]
      const int b = m0 >> 11;
      const int s0 = (m0 & 2047) + mo + quad * 4;
#pragma unroll
      for (int i = 0; i < 4; i++)
#pragma unroll
        for (int j = 0; j < 4; j++) {
          int col = n0 + no + j * 16 + lm - 2 * HID;
          int h = col >> 6, d = col & 63;
          short4v pv;
#pragma unroll
          for (int r = 0; r < 4; r++) pv[r] = f2b(acc[i][j][r]);
          *(short4v*)&vT[((size_t)(b * NHEAD + h) * HDIM + d) * S_LEN + s0 + i * 16] = pv;
        }
    } else {  // Q/K tile -> qk[m][1536] (Q already scaled via wqkvT)
#pragma unroll
      for (int i = 0; i < 4; i++)
#pragma unroll
        for (int j = 0; j < 4; j++)
#pragma unroll
          for (int r = 0; r < 4; r++)
            Cq[(size_t)(m0 + mo + i * 16 + quad * 4 + r) * (2 * HID) + n0 + no + j * 16 + lm] =
                f2b(acc[i][j][r]);
    }
  }
}

// ---------------- MFMA flash attention, causal, fixed-max softmax ----------------
#define QTILE 128
#define PST   72

__global__ __launch_bounds__(256) void attn_mfma(const short* __restrict__ qk,
                                                 const short* __restrict__ vT,
                                                 short* __restrict__ attnout) {
  __shared__ __align__(16) short Qs[QTILE * PST];   // [m][d]
  __shared__ __align__(16) short Ks[64 * PST];      // [p][d], p key-permuted
  __shared__ __align__(16) short Vt[64 * PST];      // [d][key]
  __shared__ __align__(16) short Ps[4][16 * PST];   // per-wave [m][key]

  const int tid = threadIdx.x;
  const int w = tid >> 6, lane = tid & 63;
  const int quad = lane >> 4, lm = lane & 15;
  const int bh = blockIdx.x, qt = blockIdx.y;
  const int b = bh / NHEAD, h = bh % NHEAD;

  const size_t qbase = (size_t)(b * S_LEN + qt * QTILE) * (2 * HID) + h * HDIM;
  const size_t kbase = (size_t)(b * S_LEN) * (2 * HID) + HID + h * HDIM;
  const size_t vbase = (size_t)(b * NHEAD + h) * HDIM * S_LEN;

#pragma unroll
  for (int i = 0; i < 4; i++) {
    int flat = i * 256 + tid;
    int row = flat >> 3, c8 = (flat & 7) * 8;
    *(short8*)&Qs[row * PST + c8] =
        *(const short8*)&qk[qbase + (size_t)row * (2 * HID) + c8];
  }

  float4v o_acc[2][4];
#pragma unroll
  for (int mt = 0; mt < 2; mt++)
#pragma unroll
    for (int nt = 0; nt < 4; nt++) o_acc[mt][nt] = (float4v)0.0f;
  float lsum[2][4];
#pragma unroll
  for (int mt = 0; mt < 2; mt++)
#pragma unroll
    for (int r = 0; r < 4; r++) lsum[mt][r] = 0.0f;

  const int ktmax = 2 * qt + 2;
  short8 kreg[2], vreg[2];

#define PREFETCH(KT)                                                               \
  {                                                                                \
    _Pragma("unroll") for (int i = 0; i < 2; i++) {                                \
      int flat = i * 256 + tid;                                                    \
      int p = flat >> 3, c8 = (flat & 7) * 8;                                      \
      int key = 4 * (p & 15) + (p >> 4);                                           \
      kreg[i] = *(const short8*)&qk[kbase + (size_t)((KT)*64 + key) * (2*HID) + c8]; \
      vreg[i] = *(const short8*)&vT[vbase + (size_t)p * S_LEN + (KT)*64 + c8];     \
    }                                                                              \
  }

  PREFETCH(0);

  for (int kt = 0; kt < ktmax; kt++) {
    __syncthreads();
#pragma unroll
    for (int i = 0; i < 2; i++) {
      int flat = i * 256 + tid;
      int p = flat >> 3, c8 = (flat & 7) * 8;
      *(short8*)&Ks[p * PST + c8] = kreg[i];
      *(short8*)&Vt[p * PST + c8] = vreg[i];
    }
    __syncthreads();
    if (kt + 1 < ktmax) PREFETCH(kt + 1);

#pragma unroll
    for (int mt = 0; mt < 2; mt++) {
      if (mt == 0 && kt == ktmax - 1) continue;  // fully-masked tile
      float4v s_acc[4];
#pragma unroll
      for (int i = 0; i < 4; i++) s_acc[i] = (float4v)0.0f;
#pragma unroll
      for (int kb = 0; kb < 2; kb++) {
        short8 a = *(const short8*)&Qs[(mt * 64 + w * 16 + lm) * PST + kb * 32 + quad * 8];
#pragma unroll
        for (int nt = 0; nt < 4; nt++) {
          short8 bk = *(const short8*)&Ks[(nt * 16 + lm) * PST + kb * 32 + quad * 8];
          s_acc[nt] = __builtin_amdgcn_mfma_f32_16x16x32_bf16(a, bk, s_acc[nt], 0, 0, 0);
        }
      }

      const bool diag = (kt == 2 * qt + mt);
#pragma unroll
      for (int r = 0; r < 4; r++) {
        short4v p4;
#pragma unroll
        for (int nt = 0; nt < 4; nt++) {
          float e = __expf(s_acc[nt][r]);  // fixed-max softmax: exact, no reductions
          if (diag && (4 * lm + nt > w * 16 + quad * 4 + r)) e = 0.0f;
          lsum[mt][r] += e;
          p4[nt] = f2b(e);
        }
        *(short4v*)&Ps[w][(quad * 4 + r) * PST + lm * 4] = p4;  // key = 4*lm+nt
      }

#pragma unroll
      for (int kb = 0; kb < 2; kb++) {
        short8 a = *(const short8*)&Ps[w][lm * PST + kb * 32 + quad * 8];
#pragma unroll
        for (int nt = 0; nt < 4; nt++) {
          short8 bv = *(const short8*)&Vt[(nt * 16 + lm) * PST + kb * 32 + quad * 8];
          o_acc[mt][nt] = __builtin_amdgcn_mfma_f32_16x16x32_bf16(a, bv, o_acc[mt][nt], 0, 0, 0);
        }
      }
    }
  }

#pragma unroll
  for (int mt = 0; mt < 2; mt++)
#pragma unroll
    for (int r = 0; r < 4; r++) {
#pragma unroll
      for (int off = 1; off < 16; off <<= 1)
        lsum[mt][r] += __shfl_xor(lsum[mt][r], off, 16);
      float inv = 1.0f / lsum[mt][r];
      int rowg = b * S_LEN + qt * QTILE + mt * 64 + w * 16 + quad * 4 + r;
#pragma unroll
      for (int nt = 0; nt < 4; nt++)
        attnout[(size_t)rowg * HID + h * HDIM + nt * 16 + lm] =
            f2b(o_acc[mt][nt][r] * inv);
    }
}

extern "C" void kernel_launch(void* const* d_in, const int* in_sizes, int n_in,
                              void* d_out, int out_size, void* d_ws, size_t ws_size,
                              hipStream_t stream) {
  const float* x     = (const float*)d_in[0];
  const float* w_qkv = (const float*)d_in[1];
  const float* w_out = (const float*)d_in[2];
  float* out = (float*)d_out;

  const int M = BATCH * S_LEN;  // 8192
  short* qk     = (short*)d_ws;                       // [8192][1536] bf16
  short* attn   = qk + (size_t)M * 2 * HID;           // [8192][768]  bf16
  short* vT     = attn + (size_t)M * HID;             // [B][NH][64][2048] bf16
  short* xb     = vT + (size_t)M * HID;               // [8192][768]  bf16
  short* wqkvT  = xb + (size_t)M * HID;               // [2304][768]  bf16 (Q rows pre-scaled)
  short* woutT  = wqkvT + (size_t)(3 * HID) * HID;    // [768][768]   bf16

  cvt_bf16<<<M * HID / 2048, 256, 0, stream>>>(x, xb);
  transpose_w<<<dim3(3 * HID / 64, HID / 64), 256, 0, stream>>>(w_qkv, wqkvT, HID, 3 * HID, HID);
  transpose_w<<<dim3(HID / 64, HID / 64), 256, 0, stream>>>(w_out, woutT, HID, HID, 0);

  gemm_bt<1><<<dim3(3 * HID / 128, M / 128), 256, 0, stream>>>(
      xb, wqkvT, nullptr, qk, vT, M, 3 * HID, HID);
  attn_mfma<<<dim3(BATCH * NHEAD, S_LEN / QTILE), 256, 0, stream>>>(qk, vT, attn);
  gemm_bt<0><<<dim3(HID / 128, M / 128), 256, 0, stream>>>(
      attn, woutT, out, nullptr, nullptr, M, HID, HID);
}

// Round 5
// 213.201 us; speedup vs baseline: 5.6299x; 1.0899x over previous
//
#include <hip/hip_runtime.h>
#include <type_traits>

#define S_LEN 2048
#define HID   768
#define NHEAD 12
#define HDIM  64
#define BATCH 4

typedef __attribute__((ext_vector_type(4))) float float4v;
typedef __attribute__((ext_vector_type(8))) short short8;
typedef __attribute__((ext_vector_type(4))) short short4v;

__device__ __forceinline__ short f2b(float f) {
  unsigned u = __float_as_uint(f);
  u += 0x7fff + ((u >> 16) & 1);   // RNE
  return (short)(u >> 16);
}

__device__ __forceinline__ float fexp2(float x) {
#if __has_builtin(__builtin_amdgcn_exp2f)
  return __builtin_amdgcn_exp2f(x);
#else
  return __expf(x * 0.69314718056f);
#endif
}

// async global->LDS, 16 B per lane; lds base must be wave-uniform
__device__ __forceinline__ void g2l16(const short* g, short* l) {
  __builtin_amdgcn_global_load_lds(
      (const __attribute__((address_space(1))) void*)g,
      (__attribute__((address_space(3))) void*)l, 16, 0, 0);
}

// ---------------- pre-pass: fp32 -> bf16 convert ----------------
__global__ __launch_bounds__(256) void cvt_bf16(const float* __restrict__ X,
                                                short* __restrict__ Xb) {
  int i = (blockIdx.x * 256 + threadIdx.x) * 8;
  float4v a = *(const float4v*)&X[i];
  float4v b = *(const float4v*)&X[i + 4];
  short8 o;
#pragma unroll
  for (int j = 0; j < 4; j++) { o[j] = f2b(a[j]); o[j + 4] = f2b(b[j]); }
  *(short8*)&Xb[i] = o;
}

// ---------------- pre-pass: W[K_][N_] f32 -> WT[N_][K_] bf16 (+row scale) ----
// Q rows scaled by 0.125*log2(e) so attention can use native exp2.
__global__ __launch_bounds__(256) void transpose_w(const float* __restrict__ W,
                                                   short* __restrict__ WT,
                                                   int K_, int N_, int scaleN) {
  __shared__ float tile[64][65];
  const int n0 = blockIdx.x * 64, k0 = blockIdx.y * 64;
  const int tx = threadIdx.x & 63, ty = threadIdx.x >> 6;
#pragma unroll
  for (int r = 0; r < 16; r++) {
    int row = r * 4 + ty;
    tile[row][tx] = W[(size_t)(k0 + row) * N_ + n0 + tx];
  }
  __syncthreads();
#pragma unroll
  for (int r = 0; r < 16; r++) {
    int row = r * 4 + ty;
    float sc = (n0 + row < scaleN) ? 0.18033688011f : 1.0f;  // 0.125*log2e
    WT[(size_t)(n0 + row) * K_ + k0 + tx] = f2b(tile[tx][row] * sc);
  }
}

// ---------------- m97-style bf16 GEMM: C[MxN] = A[MxK] * Bt[NxK]^T ----------
template <int OUT>
__global__ __launch_bounds__(256) void gemm_bt(const short* __restrict__ A,
                                               const short* __restrict__ Bt,
                                               float* __restrict__ Cf,
                                               short* __restrict__ Cq,
                                               short* __restrict__ vT,
                                               int M, int N, int K) {
  __shared__ __align__(16) short As[128 * 32];  // [m][k] contiguous (g2l16 layout)
  __shared__ __align__(16) short Bs[128 * 32];  // [n][k] contiguous
  const int tid = threadIdx.x;
  const int w = tid >> 6, lane = tid & 63;
  const int quad = lane >> 4, lm = lane & 15;
  const int m0 = blockIdx.y * 128, n0 = blockIdx.x * 128;
  const int mo = (w & 1) * 64, no = (w >> 1) * 64;

  float4v acc[4][4];
#pragma unroll
  for (int i = 0; i < 4; i++)
#pragma unroll
    for (int j = 0; j < 4; j++) acc[i][j] = (float4v)0.0f;

  const int srow = w * 32 + (lane >> 2);
  const int scol = (lane & 3) * 8;
  const short* Ag = A + (size_t)(m0 + srow) * K + scol;
  const short* Bg = Bt + (size_t)(n0 + srow) * K + scol;
  short* Al = &As[(w * 32) * 32];
  short* Bl = &Bs[(w * 32) * 32];

  for (int kb = 0; kb < K; kb += 32) {
    g2l16(Ag + kb, Al);
    g2l16(Ag + kb + (size_t)16 * K, Al + 16 * 32);
    g2l16(Bg + kb, Bl);
    g2l16(Bg + kb + (size_t)16 * K, Bl + 16 * 32);
    __syncthreads();

    short8 af[4], bf[4];
#pragma unroll
    for (int i = 0; i < 4; i++)
      af[i] = *(const short8*)&As[(mo + i * 16 + lm) * 32 + quad * 8];
#pragma unroll
    for (int j = 0; j < 4; j++)
      bf[j] = *(const short8*)&Bs[(no + j * 16 + lm) * 32 + quad * 8];
#pragma unroll
    for (int i = 0; i < 4; i++)
#pragma unroll
      for (int j = 0; j < 4; j++)
        acc[i][j] = __builtin_amdgcn_mfma_f32_16x16x32_bf16(af[i], bf[j], acc[i][j], 0, 0, 0);
    __syncthreads();
  }

  if constexpr (OUT == 0) {
#pragma unroll
    for (int i = 0; i < 4; i++)
#pragma unroll
      for (int j = 0; j < 4; j++)
#pragma unroll
        for (int r = 0; r < 4; r++)
          Cf[(size_t)(m0 + mo + i * 16 + quad * 4 + r) * N + n0 + no + j * 16 + lm] =
              acc[i][j][r];
  } else {
    if (n0 >= 2 * HID) {  // V tile -> vT[b][h][d][s]
      const int b = m0 >> 11;
      const int s0 = (m0 & 2047) + mo + quad * 4;
#pragma unroll
      for (int i = 0; i < 4; i++)
#pragma unroll
        for (int j = 0; j < 4; j++) {
          int col = n0 + no + j * 16 + lm - 2 * HID;
          int h = col >> 6, d = col & 63;
          short4v pv;
#pragma unroll
          for (int r = 0; r < 4; r++) pv[r] = f2b(acc[i][j][r]);
          *(short4v*)&vT[((size_t)(b * NHEAD + h) * HDIM + d) * S_LEN + s0 + i * 16] = pv;
        }
    } else {  // Q/K tile -> qk[m][1536]
#pragma unroll
      for (int i = 0; i < 4; i++)
#pragma unroll
        for (int j = 0; j < 4; j++)
#pragma unroll
          for (int r = 0; r < 4; r++)
            Cq[(size_t)(m0 + mo + i * 16 + quad * 4 + r) * (2 * HID) + n0 + no + j * 16 + lm] =
                f2b(acc[i][j][r]);
    }
  }
}

// ---------------- MFMA flash attention, causal, fixed-max softmax ----------------
// Balanced pairing: block (bh, a) handles q-tiles qtA=a and qtB=31-a (64 rows each).
// Every block does exactly (a+1)+(32-a)=33 tile-computations -> flat tail.
#define PST 72

__global__ __launch_bounds__(256) void attn_mfma(const short* __restrict__ qk,
                                                 const short* __restrict__ vT,
                                                 short* __restrict__ attnout) {
  __shared__ __align__(16) short Qs[128 * PST];     // rows 0..63 = tile A, 64..127 = tile B
  __shared__ __align__(16) short Ks[64 * PST];      // [p][d], p key-permuted
  __shared__ __align__(16) short Vt[64 * PST];      // [d][key]
  __shared__ __align__(16) short Ps[4][16 * PST];   // per-wave [m][key]

  const int tid = threadIdx.x;
  const int w = tid >> 6, lane = tid & 63;
  const int quad = lane >> 4, lm = lane & 15;
  const int bh = blockIdx.x, a = blockIdx.y;
  const int b = bh / NHEAD, h = bh % NHEAD;
  const int qtile[2] = {a, 31 - a};   // tile 0 = A (gated), tile 1 = B (always)

  const size_t kbase = (size_t)(b * S_LEN) * (2 * HID) + HID + h * HDIM;
  const size_t vbase = (size_t)(b * NHEAD + h) * HDIM * S_LEN;

  // stage both Q tiles
#pragma unroll
  for (int i = 0; i < 4; i++) {
    int flat = i * 256 + tid;
    int row = flat >> 3, c8 = (flat & 7) * 8;
    int grow = qtile[row >> 6] * 64 + (row & 63);
    *(short8*)&Qs[row * PST + c8] =
        *(const short8*)&qk[(size_t)(b * S_LEN + grow) * (2 * HID) + h * HDIM + c8];
  }

  float4v o_acc[2][4];
#pragma unroll
  for (int t = 0; t < 2; t++)
#pragma unroll
    for (int nt = 0; nt < 4; nt++) o_acc[t][nt] = (float4v)0.0f;
  float lsum[2][4];
#pragma unroll
  for (int t = 0; t < 2; t++)
#pragma unroll
    for (int r = 0; r < 4; r++) lsum[t][r] = 0.0f;

  const int ktmax = 32 - a;   // tile B needs kt = 0 .. 31-a
  short8 kreg[2], vreg[2];

#define PREFETCH(KT)                                                               \
  {                                                                                \
    _Pragma("unroll") for (int i = 0; i < 2; i++) {                                \
      int flat = i * 256 + tid;                                                    \
      int p = flat >> 3, c8 = (flat & 7) * 8;                                      \
      int key = 4 * (p & 15) + (p >> 4);                                           \
      kreg[i] = *(const short8*)&qk[kbase + (size_t)((KT)*64 + key) * (2*HID) + c8]; \
      vreg[i] = *(const short8*)&vT[vbase + (size_t)p * S_LEN + (KT)*64 + c8];     \
    }                                                                              \
  }

  PREFETCH(0);

  for (int kt = 0; kt < ktmax; kt++) {
    __syncthreads();
#pragma unroll
    for (int i = 0; i < 2; i++) {
      int flat = i * 256 + tid;
      int p = flat >> 3, c8 = (flat & 7) * 8;
      *(short8*)&Ks[p * PST + c8] = kreg[i];
      *(short8*)&Vt[p * PST + c8] = vreg[i];
    }
    __syncthreads();
    if (kt + 1 < ktmax) PREFETCH(kt + 1);

#pragma unroll
    for (int t = 0; t < 2; t++) {
      if (t == 0 && kt > a) continue;   // tile A done after its diagonal
      float4v s_acc[4];
#pragma unroll
      for (int i = 0; i < 4; i++) s_acc[i] = (float4v)0.0f;
#pragma unroll
      for (int kb = 0; kb < 2; kb++) {
        short8 aq = *(const short8*)&Qs[(t * 64 + w * 16 + lm) * PST + kb * 32 + quad * 8];
#pragma unroll
        for (int nt = 0; nt < 4; nt++) {
          short8 bk = *(const short8*)&Ks[(nt * 16 + lm) * PST + kb * 32 + quad * 8];
          s_acc[nt] = __builtin_amdgcn_mfma_f32_16x16x32_bf16(aq, bk, s_acc[nt], 0, 0, 0);
        }
      }

      const bool diag = (kt == qtile[t]);
#pragma unroll
      for (int r = 0; r < 4; r++) {
        short4v p4;
#pragma unroll
        for (int nt = 0; nt < 4; nt++) {
          float e = fexp2(s_acc[nt][r]);  // Q pre-scaled by 0.125*log2e
          if (diag && (4 * lm + nt > w * 16 + quad * 4 + r)) e = 0.0f;
          lsum[t][r] += e;
          p4[nt] = f2b(e);
        }
        *(short4v*)&Ps[w][(quad * 4 + r) * PST + lm * 4] = p4;  // key = 4*lm+nt
      }

#pragma unroll
      for (int kb = 0; kb < 2; kb++) {
        short8 ap = *(const short8*)&Ps[w][lm * PST + kb * 32 + quad * 8];
#pragma unroll
        for (int nt = 0; nt < 4; nt++) {
          short8 bv = *(const short8*)&Vt[(nt * 16 + lm) * PST + kb * 32 + quad * 8];
          o_acc[t][nt] = __builtin_amdgcn_mfma_f32_16x16x32_bf16(ap, bv, o_acc[t][nt], 0, 0, 0);
        }
      }
    }
  }

#pragma unroll
  for (int t = 0; t < 2; t++)
#pragma unroll
    for (int r = 0; r < 4; r++) {
#pragma unroll
      for (int off = 1; off < 16; off <<= 1)
        lsum[t][r] += __shfl_xor(lsum[t][r], off, 16);
      float inv = 1.0f / lsum[t][r];
      int rowg = b * S_LEN + qtile[t] * 64 + w * 16 + quad * 4 + r;
#pragma unroll
      for (int nt = 0; nt < 4; nt++)
        attnout[(size_t)rowg * HID + h * HDIM + nt * 16 + lm] =
            f2b(o_acc[t][nt][r] * inv);
    }
}

extern "C" void kernel_launch(void* const* d_in, const int* in_sizes, int n_in,
                              void* d_out, int out_size, void* d_ws, size_t ws_size,
                              hipStream_t stream) {
  const float* x     = (const float*)d_in[0];
  const float* w_qkv = (const float*)d_in[1];
  const float* w_out = (const float*)d_in[2];
  float* out = (float*)d_out;

  const int M = BATCH * S_LEN;  // 8192
  short* qk     = (short*)d_ws;                       // [8192][1536] bf16
  short* attn   = qk + (size_t)M * 2 * HID;           // [8192][768]  bf16
  short* vT     = attn + (size_t)M * HID;             // [B][NH][64][2048] bf16
  short* xb     = vT + (size_t)M * HID;               // [8192][768]  bf16
  short* wqkvT  = xb + (size_t)M * HID;               // [2304][768]  bf16 (Q rows pre-scaled)
  short* woutT  = wqkvT + (size_t)(3 * HID) * HID;    // [768][768]   bf16

  cvt_bf16<<<M * HID / 2048, 256, 0, stream>>>(x, xb);
  transpose_w<<<dim3(3 * HID / 64, HID / 64), 256, 0, stream>>>(w_qkv, wqkvT, HID, 3 * HID, HID);
  transpose_w<<<dim3(HID / 64, HID / 64), 256, 0, stream>>>(w_out, woutT, HID, HID, 0);

  gemm_bt<1><<<dim3(3 * HID / 128, M / 128), 256, 0, stream>>>(
      xb, wqkvT, nullptr, qk, vT, M, 3 * HID, HID);
  attn_mfma<<<dim3(BATCH * NHEAD, S_LEN / 128), 256, 0, stream>>>(qk, vT, attn);
  gemm_bt<0><<<dim3(HID / 128, M / 128), 256, 0, stream>>>(
      attn, woutT, out, nullptr, nullptr, M, HID, HID);
}